// Round 14
// baseline (923.512 us; speedup 1.0000x reference)
//
#include <hip/hip_runtime.h>

#define N_NODES 100000
#define NPG     1000
#define B_GR    100
#define HDIM    128
#define E_EDGES 1600000

typedef __attribute__((ext_vector_type(8))) short bf16x8;
typedef __attribute__((ext_vector_type(4))) float f32x4;
typedef unsigned long long u64;
typedef unsigned short u16;

// ---------- helpers ----------
__device__ __forceinline__ float sigf(float x) { return 1.f / (1.f + __expf(-x)); }
__device__ __forceinline__ float tanh_fast(float x) { return 1.f - 2.f / (__expf(2.f * x) + 1.f); }
__device__ __forceinline__ u16 f2bf(float f) {
    unsigned u = __float_as_uint(f);
    unsigned r = (u + 0x7fffu + ((u >> 16) & 1u)) >> 16;
    return (u16)r;
}
__device__ __forceinline__ float bf2f(u16 h) { return __uint_as_float(((unsigned)h) << 16); }
__device__ __forceinline__ f32x4 MF(bf16x8 a, bf16x8 b, f32x4 c) {
    return __builtin_amdgcn_mfma_f32_16x16x32_bf16(a, b, c, 0, 0, 0);
}
__device__ __forceinline__ u64 pack4(f32x4 a) {
    return (u64)f2bf(a[0]) | ((u64)f2bf(a[1]) << 16)
         | ((u64)f2bf(a[2]) << 32) | ((u64)f2bf(a[3]) << 48);
}

// ---------- XCD-pinned partitioned ELL build ----------
// partition p = blockIdx & 7 -> XCD p (dispatch round-robins consecutive blockIdx
// across the 8 XCDs). All writers of dst-partition p run on XCD p, so its 3.2MB
// ELL slice + cnt slice stay in that XCD's private L2: scattered 4B writes
// accumulate per-line and write back once (~26MB total, vs 88-96MB when all 8
// XCDs dirtied every line). Edge list read 8x (once per partition), L3-absorbed.
__global__ void k_buildx(const int* __restrict__ src, const int* __restrict__ dst,
                         int* __restrict__ cnt, int* __restrict__ ell) {
    int p = blockIdx.x & 7;           // dst partition == XCD
    int g = blockIdx.x >> 3;          // edge chunk 0..31
    int lo = p * 12500, hi = lo + 12500;
    int e1 = (g + 1) * 50000;
    for (int e = g * 50000 + threadIdx.x; e < e1; e += 256) {
        int d = dst[e];
        if (d >= lo && d < hi) {
            int pos = atomicAdd(&cnt[d], 1);
            if (pos < 64) ell[(size_t)d * 64 + pos] = src[e];
        }
    }
}

// ---------- conv0: wave per node via ELL, shuffle reduce, bf16 out ----------
__global__ __launch_bounds__(256)
void k_conv0w(const float* __restrict__ x, const int* __restrict__ cnt, const int* __restrict__ ell,
              const float* __restrict__ Ws, const float* __restrict__ Wn, const float* __restrict__ b,
              u16* __restrict__ Hbf) {
    int n = blockIdx.x * 4 + (threadIdx.x >> 6);
    int lane = threadIdx.x & 63;
    if (n >= N_NODES) return;
    int degt = cnt[n];
    int deg = min(degt, 64);
    float a0 = 0.f, a1 = 0.f, a2 = 0.f;
    if (lane < deg) {
        int s = ell[(size_t)n * 64 + lane];
        a0 = x[s * 3 + 0]; a1 = x[s * 3 + 1]; a2 = x[s * 3 + 2];
    }
#pragma unroll
    for (int off = 1; off < 64; off <<= 1) {
        a0 += __shfl_xor(a0, off);
        a1 += __shfl_xor(a1, off);
        a2 += __shfl_xor(a2, off);
    }
    float inv = 1.f / fmaxf((float)degt, 1.f);
    a0 *= inv; a1 *= inv; a2 *= inv;
    float x0 = x[n * 3 + 0], x1 = x[n * 3 + 1], x2 = x[n * 3 + 2];
#pragma unroll
    for (int q = 0; q < 2; ++q) {
        int c = lane + 64 * q;
        float acc = b[c]
            + x0 * Ws[c] + x1 * Ws[128 + c] + x2 * Ws[256 + c]
            + a0 * Wn[c] + a1 * Wn[128 + c] + a2 * Wn[256 + c];
        Hbf[(size_t)n * 128 + c] = f2bf(fmaxf(acc, 0.f));
    }
}

// ---------- agg: wave per node via ELL, bf16 gather, bf16 out ----------
__global__ __launch_bounds__(256)
void k_agg2e(const u16* __restrict__ hin, const int* __restrict__ cnt, const int* __restrict__ ell,
             u16* __restrict__ out) {
    int wid = threadIdx.x >> 6;
    int l = threadIdx.x & 63;
    int n = blockIdx.x * 4 + wid;
    if (n >= N_NODES) return;
    int degt = cnt[n];
    int deg = min(degt, 64);
    int myidx = ell[(size_t)n * 64 + l];   // lanes >= deg hold garbage; never sourced
    float ax = 0.f, ay = 0.f;
    const unsigned* base = (const unsigned*)hin;   // 2 bf16 per u32; row = 64 u32
    int j = 0;
    for (; j + 4 <= deg; j += 4) {
        int i0 = __shfl(myidx, j);
        int i1 = __shfl(myidx, j + 1);
        int i2 = __shfl(myidx, j + 2);
        int i3 = __shfl(myidx, j + 3);
        unsigned v0 = base[(size_t)i0 * 64 + l];
        unsigned v1 = base[(size_t)i1 * 64 + l];
        unsigned v2 = base[(size_t)i2 * 64 + l];
        unsigned v3 = base[(size_t)i3 * 64 + l];
        ax += bf2f((u16)v0); ay += bf2f((u16)(v0 >> 16));
        ax += bf2f((u16)v1); ay += bf2f((u16)(v1 >> 16));
        ax += bf2f((u16)v2); ay += bf2f((u16)(v2 >> 16));
        ax += bf2f((u16)v3); ay += bf2f((u16)(v3 >> 16));
    }
    for (; j < deg; ++j) {
        int i0 = __shfl(myidx, j);
        unsigned v = base[(size_t)i0 * 64 + l];
        ax += bf2f((u16)v); ay += bf2f((u16)(v >> 16));
    }
    float dv = fmaxf((float)degt, 1.f);
    unsigned o = (unsigned)f2bf(ax / dv) | ((unsigned)f2bf(ay / dv) << 16);
    *(unsigned*)&out[(size_t)n * 128 + l * 2] = o;
}

// ---------- conv1 weight frags, hi + lo split ----------
__global__ void k_prepc(const float* __restrict__ Wself, const float* __restrict__ Wnbr,
                        u16* __restrict__ WCf) {
    int idx = blockIdx.x * 256 + threadIdx.x;   // 0..8191
    int fi = idx & 4095;
    int lo = idx >> 12;
    int lane = fi & 63;
    int colt = (fi >> 6) & 7;
    int kt = fi >> 9;
    int col = colt * 16 + (lane & 15);
    int k0 = kt * 32 + (lane >> 4) * 8;
    u16 o[8];
#pragma unroll
    for (int j = 0; j < 8; ++j) {
        int k = k0 + j;
        float v = (k < 128) ? Wself[k * 128 + col] : Wnbr[(k - 128) * 128 + col];
        u16 hi = f2bf(v);
        o[j] = lo ? f2bf(v - bf2f(hi)) : hi;
    }
    u64* dst = (u64*)(WCf + (size_t)idx * 8);
    dst[0] = (u64)o[0] | ((u64)o[1] << 16) | ((u64)o[2] << 32) | ((u64)o[3] << 48);
    dst[1] = (u64)o[4] | ((u64)o[5] << 16) | ((u64)o[6] << 32) | ((u64)o[7] << 48);
}

// ---------- conv1: MFMA, weights(A) x activations(B); hi+lo passes; writes Xf frag tiles ----------
__global__ __launch_bounds__(256, 1)
void k_conv1f(const u16* __restrict__ Hbf, const u16* __restrict__ AGbf,
              const u16* __restrict__ WCf, const float* __restrict__ bias,
              u16* __restrict__ Xf) {
    extern __shared__ __align__(16) u16 smem[];   // 131072 B: hi frags then lo frags
    int tid = threadIdx.x;
    int l = tid & 63, w = tid >> 6;
    {
        const u64* Wsrc = (const u64*)WCf;
        u64* Wd = (u64*)smem;
#pragma unroll
        for (int i = 0; i < 64; ++i)
            Wd[tid + 256 * i] = Wsrc[tid + 256 * i];
    }
    __syncthreads();
    int r0 = blockIdx.x * 256 + w * 64;

#pragma unroll 1
    for (int g = 0; g < 4; ++g) {
        int rowA = r0 + g * 16 + (l & 15);
        int row = min(rowA, N_NODES - 1);
        int koff = (l >> 4) * 8;
        bf16x8 act[8];
#pragma unroll
        for (int kt = 0; kt < 4; ++kt) {
            act[kt]     = *(const bf16x8*)(Hbf  + (size_t)row * 128 + kt * 32 + koff);
            act[4 + kt] = *(const bf16x8*)(AGbf + (size_t)row * 128 + kt * 32 + koff);
        }
        f32x4 acc[8];
#pragma unroll
        for (int c = 0; c < 8; ++c) acc[c] = (f32x4){0.f, 0.f, 0.f, 0.f};
#pragma unroll
        for (int kt = 0; kt < 8; ++kt)
#pragma unroll
            for (int colt = 0; colt < 8; ++colt) {
                bf16x8 wf = *(const bf16x8*)(smem + ((kt * 8 + colt) * 64 + l) * 8);
                acc[colt] = MF(wf, act[kt], acc[colt]);
            }
#pragma unroll
        for (int kt = 0; kt < 8; ++kt)
#pragma unroll
            for (int colt = 0; colt < 8; ++colt) {
                bf16x8 wf = *(const bf16x8*)(smem + 32768 + ((kt * 8 + colt) * 64 + l) * 8);
                acc[colt] = MF(wf, act[kt], acc[colt]);
            }
        if (rowA < N_NODES) {
            int t = rowA / 1000;
            int rv = rowA - t * 1000;
            int rb2 = rv >> 4, rr = rv & 15;
            size_t tilebase = (size_t)(t * 63 + rb2) * 2048 + rr * 8;
#pragma unroll
            for (int colt = 0; colt < 8; ++colt) {
                int col0 = colt * 16 + ((l >> 4) << 2);
                f32x4 v;
#pragma unroll
                for (int reg = 0; reg < 4; ++reg)
                    v[reg] = fmaxf(acc[colt][reg] + bias[col0 + reg], 0.f);
                size_t idx = tilebase + (size_t)((col0 >> 5) * 512 + ((col0 >> 3) & 3) * 128 + (col0 & 7));
                *(u64*)(Xf + idx) = pack4(v);
            }
        }
    }
}

// ---------- LSTM weight prep (B-frag order per layer) ----------
__global__ void k_prepf(const float* __restrict__ Wih0, const float* __restrict__ Whh0,
                        const float* __restrict__ Wih1, const float* __restrict__ Whh1,
                        u16* __restrict__ WTf) {
    int idx = blockIdx.x * 256 + threadIdx.x;   // 0..32767
    int lane = idx & 63;
    int gt = (idx >> 6) & 3;
    int kt = (idx >> 8) & 7;
    int w  = (idx >> 11) & 7;
    int l  = idx >> 14;
    int d = 16 * w + (lane & 15);
    int k0 = kt * 32 + (lane >> 4) * 8;
    int wrow = gt * 128 + d;
    const float* Wi = l ? Wih1 : Wih0;
    const float* Wh = l ? Whh1 : Whh0;
    const float* srcp = (k0 < 128) ? (Wi + wrow * 128 + k0) : (Wh + wrow * 128 + (k0 - 128));
    u16 o[8];
#pragma unroll
    for (int j = 0; j < 8; ++j) o[j] = f2bf(srcp[j]);
    u64* dst = (u64*)(WTf + (size_t)idx * 8);
    dst[0] = (u64)o[0] | ((u64)o[1] << 16) | ((u64)o[2] << 32) | ((u64)o[3] << 48);
    dst[1] = (u64)o[4] | ((u64)o[5] << 16) | ((u64)o[6] << 32) | ((u64)o[7] << 48);
}

__global__ void k_bsum(const float* __restrict__ bih0, const float* __restrict__ bhh0,
                       const float* __restrict__ bih1, const float* __restrict__ bhh1,
                       float* __restrict__ bs) {
    int i = blockIdx.x * 256 + threadIdx.x; // 0..1023
    int l = i >> 9, c = i & 511;
    bs[i] = l ? (bih1[c] + bhh1[c]) : (bih0[c] + bhh0[c]);
}

// ---------- A: time-parallel x-GEMM, Wih in LDS: Gx[t] = x_t @ Wih + b (bf16 out) ----------
__global__ __launch_bounds__(512, 1)
void k_gemmA(const u16* __restrict__ src, const u16* __restrict__ WTf,
             const float* __restrict__ bsB, u16* __restrict__ Gx, int t0, int layer) {
    extern __shared__ __align__(16) u16 smem[];   // 131072 B = Wih frags
    int tid = threadIdx.x;
    int l = tid & 63, w = tid >> 6;
    int rb = blockIdx.x % 63;
    int slice = blockIdx.x / 63;
    {
        const u64* Wsrc = (const u64*)(WTf + (size_t)layer * 131072);
        u64* Wd = (u64*)smem;
#pragma unroll
        for (int i = 0; i < 32; ++i) {
            int j = tid + i * 512;
            int dfrag = j >> 7, r = j & 127;
            int w_ = dfrag >> 4, kt2 = (dfrag >> 2) & 3, gt = dfrag & 3;
            int gfrag = (w_ * 8 + kt2) * 4 + gt;          // kh=0 (Wih)
            Wd[j] = Wsrc[(size_t)gfrag * 128 + r];
        }
    }
    __syncthreads();
    int d = (w << 4) | (l & 15);
    float b0v = bsB[layer * 512 + d];
    float b1v = bsB[layer * 512 + 128 + d];
    float b2v = bsB[layer * 512 + 256 + d];
    float b3v = bsB[layer * 512 + 384 + d];
    const u16* wbase = smem + (size_t)w * 8192 + l * 8;
    for (int tt = 0; tt < 10; ++tt) {
        int t = t0 + slice * 10 + tt;
        const u16* xb = src + ((size_t)t * 63 + rb) * 2048 + l * 8;
        bf16x8 x0 = *(const bf16x8*)(xb);
        bf16x8 x1 = *(const bf16x8*)(xb + 512);
        bf16x8 x2 = *(const bf16x8*)(xb + 1024);
        bf16x8 x3 = *(const bf16x8*)(xb + 1536);
        f32x4 a0 = {b0v, b0v, b0v, b0v};
        f32x4 a1 = {b1v, b1v, b1v, b1v};
        f32x4 a2 = {b2v, b2v, b2v, b2v};
        f32x4 a3 = {b3v, b3v, b3v, b3v};
#pragma unroll
        for (int kt2 = 0; kt2 < 4; ++kt2) {
            bf16x8 xa = (kt2 == 0) ? x0 : (kt2 == 1) ? x1 : (kt2 == 2) ? x2 : x3;
            a0 = MF(xa, *(const bf16x8*)(wbase + (kt2 * 4 + 0) * 512), a0);
            a1 = MF(xa, *(const bf16x8*)(wbase + (kt2 * 4 + 1) * 512), a1);
            a2 = MF(xa, *(const bf16x8*)(wbase + (kt2 * 4 + 2) * 512), a2);
            a3 = MF(xa, *(const bf16x8*)(wbase + (kt2 * 4 + 3) * 512), a3);
        }
        size_t gbase = ((size_t)(t - t0) * 63 + rb) * 8192 + (size_t)w * 1024 + l * 4;
        *(u64*)(Gx + gbase)       = pack4(a0);
        *(u64*)(Gx + gbase + 256) = pack4(a1);
        *(u64*)(Gx + gbase + 512) = pack4(a2);
        *(u64*)(Gx + gbase + 768) = pack4(a3);
    }
}

// ---------- B: recurrence only, Whh in LDS; 50-step chunk with h/c state in global ----------
__global__ __launch_bounds__(512, 1)
void k_recB(const u16* __restrict__ Gx, const u16* __restrict__ WTf,
            u16* __restrict__ H0f, float* __restrict__ pooled,
            u16* __restrict__ hstate, float* __restrict__ cstate,
            int t0, int layer) {
    extern __shared__ __align__(16) u16 smem[];
    u16* Wlds = smem;             // 131072 B = Whh frags
    u16* hshA = smem + 65536;     // 4096 B = 512 u64
    u16* hshB = smem + 67584;     // 4096 B
    int tid = threadIdx.x;
    int l = tid & 63, w = tid >> 6;
    int rb = blockIdx.x;

    // FULL h-tile init: 512 u64 across all 512 threads
    {
        u64 hv = (t0 == 0) ? 0ull : ((const u64*)(hstate + (size_t)rb * 2048))[tid];
        ((u64*)hshA)[tid] = hv;
    }
    {
        const u64* Wsrc = (const u64*)(WTf + (size_t)layer * 131072);
        u64* Wd = (u64*)Wlds;
#pragma unroll
        for (int i = 0; i < 32; ++i) {
            int j = tid + i * 512;
            int dfrag = j >> 7, r = j & 127;
            int w_ = dfrag >> 4, kt2 = (dfrag >> 2) & 3, gt = dfrag & 3;
            int gfrag = (w_ * 8 + 4 + kt2) * 4 + gt;      // kh=1 (Whh)
            Wd[j] = Wsrc[(size_t)gfrag * 128 + r];
        }
    }
    float cst0, cst1, cst2, cst3;
    if (t0 == 0) {
        cst0 = cst1 = cst2 = cst3 = 0.f;
    } else {
        const f32x4 cv = *(const f32x4*)(cstate + ((size_t)rb * 512 + tid) * 4);
        cst0 = cv[0]; cst1 = cv[1]; cst2 = cv[2]; cst3 = cv[3];
    }
    __syncthreads();

    int d = (w << 4) | (l & 15);
    int ktp = d >> 5, oct = (d >> 3) & 3, boff = d & 7;
    int hbase = ktp * 512 + ((l >> 4) * 4 + 16 * oct) * 8 + boff;
    const u16* wbase = Wlds + (size_t)w * 8192 + l * 8;
    int n0 = rb * 16;
    int nreal = min(16, NPG - n0);
    int cur = 0;

    for (int tt = 0; tt < 50; ++tt) {
        int t = t0 + tt;
        size_t gbase = ((size_t)tt * 63 + rb) * 8192 + (size_t)w * 1024 + l * 4;
        u64 p0 = *(const u64*)(Gx + gbase);
        u64 p1 = *(const u64*)(Gx + gbase + 256);
        u64 p2 = *(const u64*)(Gx + gbase + 512);
        u64 p3 = *(const u64*)(Gx + gbase + 768);

        const u16* hc = cur ? hshB : hshA;
        u16* hn = cur ? hshA : hshB;
        f32x4 a0 = {0.f, 0.f, 0.f, 0.f};
        f32x4 a1 = {0.f, 0.f, 0.f, 0.f};
        f32x4 a2 = {0.f, 0.f, 0.f, 0.f};
        f32x4 a3 = {0.f, 0.f, 0.f, 0.f};
#pragma unroll
        for (int kt2 = 0; kt2 < 4; ++kt2) {
            bf16x8 hf = *(const bf16x8*)(hc + kt2 * 512 + l * 8);
            a0 = MF(hf, *(const bf16x8*)(wbase + (kt2 * 4 + 0) * 512), a0);
            a1 = MF(hf, *(const bf16x8*)(wbase + (kt2 * 4 + 1) * 512), a1);
            a2 = MF(hf, *(const bf16x8*)(wbase + (kt2 * 4 + 2) * 512), a2);
            a3 = MF(hf, *(const bf16x8*)(wbase + (kt2 * 4 + 3) * 512), a3);
        }
        float hsum = 0.f;
#pragma unroll
        for (int reg = 0; reg < 4; ++reg) {
            float gi = a0[reg] + bf2f((u16)(p0 >> (16 * reg)));
            float gf = a1[reg] + bf2f((u16)(p1 >> (16 * reg)));
            float gg = a2[reg] + bf2f((u16)(p2 >> (16 * reg)));
            float go = a3[reg] + bf2f((u16)(p3 >> (16 * reg)));
            float cprev = (reg == 0) ? cst0 : (reg == 1) ? cst1 : (reg == 2) ? cst2 : cst3;
            float c = sigf(gf) * cprev + sigf(gi) * tanh_fast(gg);
            if (reg == 0) cst0 = c; else if (reg == 1) cst1 = c;
            else if (reg == 2) cst2 = c; else cst3 = c;
            float h = sigf(go) * tanh_fast(c);
            u16 hb = f2bf(h);
            hn[hbase + reg * 8] = hb;
            if (layer == 0) {
                H0f[((size_t)t * 63 + rb) * 2048 + hbase + reg * 8] = hb;
            } else {
                int row = (l >> 4) * 4 + reg;
                if (row < nreal) hsum += h;
            }
        }
        if (layer == 1) {
            hsum += __shfl_xor(hsum, 16);
            hsum += __shfl_xor(hsum, 32);
            if ((l >> 4) == 0) atomicAdd(&pooled[t * 128 + d], hsum);
        }
        __syncthreads();
        cur ^= 1;
    }
    ((u64*)(hstate + (size_t)rb * 2048))[tid] = ((const u64*)(cur ? hshB : hshA))[tid];
    f32x4 cv = {cst0, cst1, cst2, cst3};
    *(f32x4*)(cstate + ((size_t)rb * 512 + tid) * 4) = cv;
}

// ---------- head ----------
__global__ void k_head(const float* __restrict__ pooled, const float* __restrict__ Wout,
                       const float* __restrict__ bout, float* __restrict__ out) {
    int gi = threadIdx.x;
    if (gi >= B_GR) return;
    float l0 = bout[0], l1 = bout[1];
    for (int d = 0; d < 128; ++d) {
        float p = pooled[gi * 128 + d] / 1000.0f;
        l0 += p * Wout[d * 2 + 0];
        l1 += p * Wout[d * 2 + 1];
    }
    float m = fmaxf(l0, l1);
    float lse = m + logf(__expf(l0 - m) + __expf(l1 - m));
    out[gi * 2 + 0] = l0 - lse;
    out[gi * 2 + 1] = l1 - lse;
}

// ---------- launch ----------
extern "C" void kernel_launch(void* const* d_in, const int* in_sizes, int n_in,
                              void* d_out, int out_size, void* d_ws, size_t ws_size,
                              hipStream_t stream) {
    const float* x    = (const float*)d_in[0];
    const int*   ei   = (const int*)d_in[1];
    const int*   srcI = ei;
    const int*   dstI = ei + E_EDGES;
    const float* Ws0  = (const float*)d_in[3];
    const float* Wn0  = (const float*)d_in[4];
    const float* b0   = (const float*)d_in[5];
    const float* Ws1  = (const float*)d_in[6];
    const float* Wn1  = (const float*)d_in[7];
    const float* b1   = (const float*)d_in[8];
    const float* Wih0 = (const float*)d_in[9];
    const float* Whh0 = (const float*)d_in[10];
    const float* bih0 = (const float*)d_in[11];
    const float* bhh0 = (const float*)d_in[12];
    const float* Wih1 = (const float*)d_in[13];
    const float* Whh1 = (const float*)d_in[14];
    const float* bih1 = (const float*)d_in[15];
    const float* bhh1 = (const float*)d_in[16];
    const float* Wout = (const float*)d_in[17];
    const float* bout = (const float*)d_in[18];
    float* out = (float*)d_out;

    char* ws = (char*)d_ws;
    // conv-phase layout
    int*   cnt    = (int*)(ws + 0);             // 400,128 B (padded)
    int*   ell    = (int*)(ws + 400128);        // 25,600,000 -> 26,000,128
    u16*   Hbf    = (u16*)(ws + 26000128);      // 25,600,000 -> 51,600,128
    u16*   AGbf   = (u16*)(ws + 51600128);      // 25,600,000 -> 77,200,128
    u16*   Xf     = (u16*)(ws + 77414400);      // 25,804,800 -> 103,219,200
    u16*   WTf    = (u16*)(ws + 103219200);     //    524,288 -> 103,743,488
    float* bsB    = (float*)(ws + 103743488);   //      4,096 -> 103,747,584
    float* pooled = (float*)(ws + 103747584);   //     51,200 -> 103,798,784
    u16*   hstate = (u16*)(ws + 103798784);     //    258,048 -> 104,056,832
    float* cstate = (float*)(ws + 104056832);   //    516,096 -> 104,572,928
    u16*   WCf    = (u16*)(ws + 104572928);     //    262,144 -> 104,835,072
    // LSTM-phase reuse (cnt/ell/Hbf/AGbf dead after conv1f):
    u16*   H0f    = (u16*)(ws + 0);             // 25,804,800 -> 25,804,800
    u16*   Gx     = (u16*)(ws + 25804800);      // 51,609,600 -> 77,414,400 (== Xf start)

    hipMemsetAsync(cnt, 0, 400128, stream);
    hipMemsetAsync(pooled, 0, B_GR * 128 * sizeof(float), stream);

    k_buildx<<<256, 256, 0, stream>>>(srcI, dstI, cnt, ell);
    k_conv0w<<<N_NODES / 4, 256, 0, stream>>>(x, cnt, ell, Ws0, Wn0, b0, Hbf);
    k_agg2e<<<N_NODES / 4, 256, 0, stream>>>(Hbf, cnt, ell, AGbf);
    k_prepc<<<32, 256, 0, stream>>>(Ws1, Wn1, WCf);

    hipFuncSetAttribute((const void*)k_conv1f, hipFuncAttributeMaxDynamicSharedMemorySize, 131072);
    hipFuncSetAttribute((const void*)k_gemmA,  hipFuncAttributeMaxDynamicSharedMemorySize, 131072);
    hipFuncSetAttribute((const void*)k_recB,   hipFuncAttributeMaxDynamicSharedMemorySize, 139264);

    k_conv1f<<<(N_NODES + 255) / 256, 256, 131072, stream>>>(Hbf, AGbf, WCf, b1, Xf);

    k_prepf<<<128, 256, 0, stream>>>(Wih0, Whh0, Wih1, Whh1, WTf);
    k_bsum<<<4, 256, 0, stream>>>(bih0, bhh0, bih1, bhh1, bsB);

    for (int layer = 0; layer < 2; ++layer) {
        const u16* srcT = layer ? H0f : Xf;
        for (int half = 0; half < 2; ++half) {
            int t0 = half * 50;
            k_gemmA<<<315, 512, 131072, stream>>>(srcT, WTf, bsB, Gx, t0, layer);
            k_recB<<<63, 512, 139264, stream>>>(Gx, WTf, H0f, pooled, hstate, cstate, t0, layer);
        }
    }

    k_head<<<1, 128, 0, stream>>>(pooled, Wout, bout, out);
}

// Round 15
// 847.691 us; speedup vs baseline: 1.0894x; 1.0894x over previous
//
#include <hip/hip_runtime.h>

#define N_NODES 100000
#define NPG     1000
#define B_GR    100
#define HDIM    128
#define E_EDGES 1600000

typedef __attribute__((ext_vector_type(8))) short bf16x8;
typedef __attribute__((ext_vector_type(4))) float f32x4;
typedef unsigned long long u64;
typedef unsigned short u16;

// ---------- helpers ----------
__device__ __forceinline__ float sigf(float x) { return 1.f / (1.f + __expf(-x)); }
__device__ __forceinline__ float tanh_fast(float x) { return 1.f - 2.f / (__expf(2.f * x) + 1.f); }
__device__ __forceinline__ u16 f2bf(float f) {
    unsigned u = __float_as_uint(f);
    unsigned r = (u + 0x7fffu + ((u >> 16) & 1u)) >> 16;
    return (u16)r;
}
__device__ __forceinline__ float bf2f(u16 h) { return __uint_as_float(((unsigned)h) << 16); }
__device__ __forceinline__ f32x4 MF(bf16x8 a, bf16x8 b, f32x4 c) {
    return __builtin_amdgcn_mfma_f32_16x16x32_bf16(a, b, c, 0, 0, 0);
}
__device__ __forceinline__ u64 pack4(f32x4 a) {
    return (u64)f2bf(a[0]) | ((u64)f2bf(a[1]) << 16)
         | ((u64)f2bf(a[2]) << 32) | ((u64)f2bf(a[3]) << 48);
}
// barrier that drains LDS ops only (no vmcnt(0) drain of global prefetch)
#define BAR() asm volatile("s_waitcnt lgkmcnt(0)\n\ts_barrier" ::: "memory")

// ---------- one-pass ELL build (R12 version: best measured, ~125us) ----------
__global__ void k_build(const int* __restrict__ src, const int* __restrict__ dst,
                        int* __restrict__ cnt, int* __restrict__ ell) {
    int e = blockIdx.x * 256 + threadIdx.x;
    if (e >= E_EDGES) return;
    int d = dst[e];
    int pos = atomicAdd(&cnt[d], 1);
    if (pos < 64) ell[(size_t)d * 64 + pos] = src[e];
}

// ---------- conv0: wave per node via ELL, shuffle reduce, bf16 out ----------
__global__ __launch_bounds__(256)
void k_conv0w(const float* __restrict__ x, const int* __restrict__ cnt, const int* __restrict__ ell,
              const float* __restrict__ Ws, const float* __restrict__ Wn, const float* __restrict__ b,
              u16* __restrict__ Hbf) {
    int n = blockIdx.x * 4 + (threadIdx.x >> 6);
    int lane = threadIdx.x & 63;
    if (n >= N_NODES) return;
    int degt = cnt[n];
    int deg = min(degt, 64);
    float a0 = 0.f, a1 = 0.f, a2 = 0.f;
    if (lane < deg) {
        int s = ell[(size_t)n * 64 + lane];
        a0 = x[s * 3 + 0]; a1 = x[s * 3 + 1]; a2 = x[s * 3 + 2];
    }
#pragma unroll
    for (int off = 1; off < 64; off <<= 1) {
        a0 += __shfl_xor(a0, off);
        a1 += __shfl_xor(a1, off);
        a2 += __shfl_xor(a2, off);
    }
    float inv = 1.f / fmaxf((float)degt, 1.f);
    a0 *= inv; a1 *= inv; a2 *= inv;
    float x0 = x[n * 3 + 0], x1 = x[n * 3 + 1], x2 = x[n * 3 + 2];
#pragma unroll
    for (int q = 0; q < 2; ++q) {
        int c = lane + 64 * q;
        float acc = b[c]
            + x0 * Ws[c] + x1 * Ws[128 + c] + x2 * Ws[256 + c]
            + a0 * Wn[c] + a1 * Wn[128 + c] + a2 * Wn[256 + c];
        Hbf[(size_t)n * 128 + c] = f2bf(fmaxf(acc, 0.f));
    }
}

// ---------- agg: wave per node via ELL, bf16 gather, bf16 out ----------
__global__ __launch_bounds__(256)
void k_agg2e(const u16* __restrict__ hin, const int* __restrict__ cnt, const int* __restrict__ ell,
             u16* __restrict__ out) {
    int wid = threadIdx.x >> 6;
    int l = threadIdx.x & 63;
    int n = blockIdx.x * 4 + wid;
    if (n >= N_NODES) return;
    int degt = cnt[n];
    int deg = min(degt, 64);
    int myidx = ell[(size_t)n * 64 + l];   // lanes >= deg hold garbage; never sourced
    float ax = 0.f, ay = 0.f;
    const unsigned* base = (const unsigned*)hin;   // 2 bf16 per u32; row = 64 u32
    int j = 0;
    for (; j + 4 <= deg; j += 4) {
        int i0 = __shfl(myidx, j);
        int i1 = __shfl(myidx, j + 1);
        int i2 = __shfl(myidx, j + 2);
        int i3 = __shfl(myidx, j + 3);
        unsigned v0 = base[(size_t)i0 * 64 + l];
        unsigned v1 = base[(size_t)i1 * 64 + l];
        unsigned v2 = base[(size_t)i2 * 64 + l];
        unsigned v3 = base[(size_t)i3 * 64 + l];
        ax += bf2f((u16)v0); ay += bf2f((u16)(v0 >> 16));
        ax += bf2f((u16)v1); ay += bf2f((u16)(v1 >> 16));
        ax += bf2f((u16)v2); ay += bf2f((u16)(v2 >> 16));
        ax += bf2f((u16)v3); ay += bf2f((u16)(v3 >> 16));
    }
    for (; j < deg; ++j) {
        int i0 = __shfl(myidx, j);
        unsigned v = base[(size_t)i0 * 64 + l];
        ax += bf2f((u16)v); ay += bf2f((u16)(v >> 16));
    }
    float dv = fmaxf((float)degt, 1.f);
    unsigned o = (unsigned)f2bf(ax / dv) | ((unsigned)f2bf(ay / dv) << 16);
    *(unsigned*)&out[(size_t)n * 128 + l * 2] = o;
}

// ---------- conv1 weight frags, hi + lo split ----------
__global__ void k_prepc(const float* __restrict__ Wself, const float* __restrict__ Wnbr,
                        u16* __restrict__ WCf) {
    int idx = blockIdx.x * 256 + threadIdx.x;   // 0..8191
    int fi = idx & 4095;
    int lo = idx >> 12;
    int lane = fi & 63;
    int colt = (fi >> 6) & 7;
    int kt = fi >> 9;
    int col = colt * 16 + (lane & 15);
    int k0 = kt * 32 + (lane >> 4) * 8;
    u16 o[8];
#pragma unroll
    for (int j = 0; j < 8; ++j) {
        int k = k0 + j;
        float v = (k < 128) ? Wself[k * 128 + col] : Wnbr[(k - 128) * 128 + col];
        u16 hi = f2bf(v);
        o[j] = lo ? f2bf(v - bf2f(hi)) : hi;
    }
    u64* dst = (u64*)(WCf + (size_t)idx * 8);
    dst[0] = (u64)o[0] | ((u64)o[1] << 16) | ((u64)o[2] << 32) | ((u64)o[3] << 48);
    dst[1] = (u64)o[4] | ((u64)o[5] << 16) | ((u64)o[6] << 32) | ((u64)o[7] << 48);
}

// ---------- conv1: MFMA, weights(A) x activations(B); hi+lo passes; writes Xf frag tiles ----------
__global__ __launch_bounds__(256, 1)
void k_conv1f(const u16* __restrict__ Hbf, const u16* __restrict__ AGbf,
              const u16* __restrict__ WCf, const float* __restrict__ bias,
              u16* __restrict__ Xf) {
    extern __shared__ __align__(16) u16 smem[];   // 131072 B: hi frags then lo frags
    int tid = threadIdx.x;
    int l = tid & 63, w = tid >> 6;
    {
        const u64* Wsrc = (const u64*)WCf;
        u64* Wd = (u64*)smem;
#pragma unroll
        for (int i = 0; i < 64; ++i)
            Wd[tid + 256 * i] = Wsrc[tid + 256 * i];
    }
    __syncthreads();
    int r0 = blockIdx.x * 256 + w * 64;

#pragma unroll 1
    for (int g = 0; g < 4; ++g) {
        int rowA = r0 + g * 16 + (l & 15);
        int row = min(rowA, N_NODES - 1);
        int koff = (l >> 4) * 8;
        bf16x8 act[8];
#pragma unroll
        for (int kt = 0; kt < 4; ++kt) {
            act[kt]     = *(const bf16x8*)(Hbf  + (size_t)row * 128 + kt * 32 + koff);
            act[4 + kt] = *(const bf16x8*)(AGbf + (size_t)row * 128 + kt * 32 + koff);
        }
        f32x4 acc[8];
#pragma unroll
        for (int c = 0; c < 8; ++c) acc[c] = (f32x4){0.f, 0.f, 0.f, 0.f};
#pragma unroll
        for (int kt = 0; kt < 8; ++kt)
#pragma unroll
            for (int colt = 0; colt < 8; ++colt) {
                bf16x8 wf = *(const bf16x8*)(smem + ((kt * 8 + colt) * 64 + l) * 8);
                acc[colt] = MF(wf, act[kt], acc[colt]);
            }
#pragma unroll
        for (int kt = 0; kt < 8; ++kt)
#pragma unroll
            for (int colt = 0; colt < 8; ++colt) {
                bf16x8 wf = *(const bf16x8*)(smem + 32768 + ((kt * 8 + colt) * 64 + l) * 8);
                acc[colt] = MF(wf, act[kt], acc[colt]);
            }
        if (rowA < N_NODES) {
            int t = rowA / 1000;
            int rv = rowA - t * 1000;
            int rb2 = rv >> 4, rr = rv & 15;
            size_t tilebase = (size_t)(t * 63 + rb2) * 2048 + rr * 8;
#pragma unroll
            for (int colt = 0; colt < 8; ++colt) {
                int col0 = colt * 16 + ((l >> 4) << 2);
                f32x4 v;
#pragma unroll
                for (int reg = 0; reg < 4; ++reg)
                    v[reg] = fmaxf(acc[colt][reg] + bias[col0 + reg], 0.f);
                size_t idx = tilebase + (size_t)((col0 >> 5) * 512 + ((col0 >> 3) & 3) * 128 + (col0 & 7));
                *(u64*)(Xf + idx) = pack4(v);
            }
        }
    }
}

// ---------- LSTM weight prep (B-frag order per layer) ----------
__global__ void k_prepf(const float* __restrict__ Wih0, const float* __restrict__ Whh0,
                        const float* __restrict__ Wih1, const float* __restrict__ Whh1,
                        u16* __restrict__ WTf) {
    int idx = blockIdx.x * 256 + threadIdx.x;   // 0..32767
    int lane = idx & 63;
    int gt = (idx >> 6) & 3;
    int kt = (idx >> 8) & 7;
    int w  = (idx >> 11) & 7;
    int l  = idx >> 14;
    int d = 16 * w + (lane & 15);
    int k0 = kt * 32 + (lane >> 4) * 8;
    int wrow = gt * 128 + d;
    const float* Wi = l ? Wih1 : Wih0;
    const float* Wh = l ? Whh1 : Whh0;
    const float* srcp = (k0 < 128) ? (Wi + wrow * 128 + k0) : (Wh + wrow * 128 + (k0 - 128));
    u16 o[8];
#pragma unroll
    for (int j = 0; j < 8; ++j) o[j] = f2bf(srcp[j]);
    u64* dst = (u64*)(WTf + (size_t)idx * 8);
    dst[0] = (u64)o[0] | ((u64)o[1] << 16) | ((u64)o[2] << 32) | ((u64)o[3] << 48);
    dst[1] = (u64)o[4] | ((u64)o[5] << 16) | ((u64)o[6] << 32) | ((u64)o[7] << 48);
}

__global__ void k_bsum(const float* __restrict__ bih0, const float* __restrict__ bhh0,
                       const float* __restrict__ bih1, const float* __restrict__ bhh1,
                       float* __restrict__ bs) {
    int i = blockIdx.x * 256 + threadIdx.x; // 0..1023
    int l = i >> 9, c = i & 511;
    bs[i] = l ? (bih1[c] + bhh1[c]) : (bih0[c] + bhh0[c]);
}

// ---------- A: time-parallel x-GEMM, Wih in LDS; 252 blocks (<=256 CUs, 1/CU) ----------
__global__ __launch_bounds__(512, 1)
void k_gemmA(const u16* __restrict__ src, const u16* __restrict__ WTf,
             const float* __restrict__ bsB, u16* __restrict__ Gx, int t0, int layer) {
    extern __shared__ __align__(16) u16 smem[];   // 131072 B = Wih frags
    int tid = threadIdx.x;
    int l = tid & 63, w = tid >> 6;
    int rb = blockIdx.x % 63;
    int slice = blockIdx.x / 63;                  // 0..3
    int nt = (slice < 2) ? 13 : 12;               // 13+13+12+12 = 50
    int ts = (slice < 2) ? slice * 13 : 26 + (slice - 2) * 12;
    {
        const u64* Wsrc = (const u64*)(WTf + (size_t)layer * 131072);
        u64* Wd = (u64*)smem;
#pragma unroll
        for (int i = 0; i < 32; ++i) {
            int j = tid + i * 512;
            int dfrag = j >> 7, r = j & 127;
            int w_ = dfrag >> 4, kt2 = (dfrag >> 2) & 3, gt = dfrag & 3;
            int gfrag = (w_ * 8 + kt2) * 4 + gt;          // kh=0 (Wih)
            Wd[j] = Wsrc[(size_t)gfrag * 128 + r];
        }
    }
    __syncthreads();
    int d = (w << 4) | (l & 15);
    float b0v = bsB[layer * 512 + d];
    float b1v = bsB[layer * 512 + 128 + d];
    float b2v = bsB[layer * 512 + 256 + d];
    float b3v = bsB[layer * 512 + 384 + d];
    const u16* wbase = smem + (size_t)w * 8192 + l * 8;
    for (int tt = 0; tt < nt; ++tt) {
        int tc = ts + tt;                 // chunk-local t
        int t = t0 + tc;                  // global t
        const u16* xb = src + ((size_t)t * 63 + rb) * 2048 + l * 8;
        bf16x8 x0 = *(const bf16x8*)(xb);
        bf16x8 x1 = *(const bf16x8*)(xb + 512);
        bf16x8 x2 = *(const bf16x8*)(xb + 1024);
        bf16x8 x3 = *(const bf16x8*)(xb + 1536);
        f32x4 a0 = {b0v, b0v, b0v, b0v};
        f32x4 a1 = {b1v, b1v, b1v, b1v};
        f32x4 a2 = {b2v, b2v, b2v, b2v};
        f32x4 a3 = {b3v, b3v, b3v, b3v};
#pragma unroll
        for (int kt2 = 0; kt2 < 4; ++kt2) {
            bf16x8 xa = (kt2 == 0) ? x0 : (kt2 == 1) ? x1 : (kt2 == 2) ? x2 : x3;
            a0 = MF(xa, *(const bf16x8*)(wbase + (kt2 * 4 + 0) * 512), a0);
            a1 = MF(xa, *(const bf16x8*)(wbase + (kt2 * 4 + 1) * 512), a1);
            a2 = MF(xa, *(const bf16x8*)(wbase + (kt2 * 4 + 2) * 512), a2);
            a3 = MF(xa, *(const bf16x8*)(wbase + (kt2 * 4 + 3) * 512), a3);
        }
        size_t gbase = ((size_t)tc * 63 + rb) * 8192 + (size_t)w * 1024 + l * 4;
        *(u64*)(Gx + gbase)       = pack4(a0);
        *(u64*)(Gx + gbase + 256) = pack4(a1);
        *(u64*)(Gx + gbase + 512) = pack4(a2);
        *(u64*)(Gx + gbase + 768) = pack4(a3);
    }
}

// ---------- B: recurrence, Whh in LDS; LDS-only step barrier + Gx prefetch ----------
__global__ __launch_bounds__(512, 1)
void k_recB(const u16* __restrict__ Gx, const u16* __restrict__ WTf,
            u16* __restrict__ H0f, float* __restrict__ pooled,
            u16* __restrict__ hstate, float* __restrict__ cstate,
            int t0, int layer) {
    extern __shared__ __align__(16) u16 smem[];
    u16* Wlds = smem;             // 131072 B = Whh frags
    u16* hshA = smem + 65536;     // 4096 B = 512 u64
    u16* hshB = smem + 67584;     // 4096 B
    int tid = threadIdx.x;
    int l = tid & 63, w = tid >> 6;
    int rb = blockIdx.x;

    // FULL h-tile init: 512 u64 across all 512 threads
    {
        u64 hv = (t0 == 0) ? 0ull : ((const u64*)(hstate + (size_t)rb * 2048))[tid];
        ((u64*)hshA)[tid] = hv;
    }
    {
        const u64* Wsrc = (const u64*)(WTf + (size_t)layer * 131072);
        u64* Wd = (u64*)Wlds;
#pragma unroll
        for (int i = 0; i < 32; ++i) {
            int j = tid + i * 512;
            int dfrag = j >> 7, r = j & 127;
            int w_ = dfrag >> 4, kt2 = (dfrag >> 2) & 3, gt = dfrag & 3;
            int gfrag = (w_ * 8 + 4 + kt2) * 4 + gt;      // kh=1 (Whh)
            Wd[j] = Wsrc[(size_t)gfrag * 128 + r];
        }
    }
    float cst0, cst1, cst2, cst3;
    if (t0 == 0) {
        cst0 = cst1 = cst2 = cst3 = 0.f;
    } else {
        const f32x4 cv = *(const f32x4*)(cstate + ((size_t)rb * 512 + tid) * 4);
        cst0 = cv[0]; cst1 = cv[1]; cst2 = cv[2]; cst3 = cv[3];
    }
    __syncthreads();

    int d = (w << 4) | (l & 15);
    int ktp = d >> 5, oct = (d >> 3) & 3, boff = d & 7;
    int hbase = ktp * 512 + ((l >> 4) * 4 + 16 * oct) * 8 + boff;
    const u16* wbase = Wlds + (size_t)w * 8192 + l * 8;
    int n0 = rb * 16;
    int nreal = min(16, NPG - n0);
    int cur = 0;

    // prefetch Gx for tt=0
    size_t goff = (size_t)w * 1024 + l * 4;
    const u64* g0p = (const u64*)(Gx + (size_t)rb * 8192 + goff);
    u64 p0 = g0p[0], p1 = g0p[32], p2 = g0p[64], p3 = g0p[96];   // +256,+512,+768 u16 = +32,+64,+96 u64

    for (int tt = 0; tt < 50; ++tt) {
        int t = t0 + tt;
        const u16* hc = cur ? hshB : hshA;
        u16* hn = cur ? hshA : hshB;
        f32x4 a0 = {0.f, 0.f, 0.f, 0.f};
        f32x4 a1 = {0.f, 0.f, 0.f, 0.f};
        f32x4 a2 = {0.f, 0.f, 0.f, 0.f};
        f32x4 a3 = {0.f, 0.f, 0.f, 0.f};
#pragma unroll
        for (int kt2 = 0; kt2 < 4; ++kt2) {
            bf16x8 hf = *(const bf16x8*)(hc + kt2 * 512 + l * 8);
            a0 = MF(hf, *(const bf16x8*)(wbase + (kt2 * 4 + 0) * 512), a0);
            a1 = MF(hf, *(const bf16x8*)(wbase + (kt2 * 4 + 1) * 512), a1);
            a2 = MF(hf, *(const bf16x8*)(wbase + (kt2 * 4 + 2) * 512), a2);
            a3 = MF(hf, *(const bf16x8*)(wbase + (kt2 * 4 + 3) * 512), a3);
        }
        // prefetch next step's Gx (global; NOT drained by the LDS-only barrier)
        u64 q0 = 0, q1 = 0, q2 = 0, q3 = 0;
        if (tt < 49) {
            const u64* gp = (const u64*)(Gx + ((size_t)(tt + 1) * 63 + rb) * 8192 + goff);
            q0 = gp[0]; q1 = gp[32]; q2 = gp[64]; q3 = gp[96];
        }
        float hsum = 0.f;
#pragma unroll
        for (int reg = 0; reg < 4; ++reg) {
            float gi = a0[reg] + bf2f((u16)(p0 >> (16 * reg)));
            float gf = a1[reg] + bf2f((u16)(p1 >> (16 * reg)));
            float gg = a2[reg] + bf2f((u16)(p2 >> (16 * reg)));
            float go = a3[reg] + bf2f((u16)(p3 >> (16 * reg)));
            float cprev = (reg == 0) ? cst0 : (reg == 1) ? cst1 : (reg == 2) ? cst2 : cst3;
            float c = sigf(gf) * cprev + sigf(gi) * tanh_fast(gg);
            if (reg == 0) cst0 = c; else if (reg == 1) cst1 = c;
            else if (reg == 2) cst2 = c; else cst3 = c;
            float h = sigf(go) * tanh_fast(c);
            u16 hb = f2bf(h);
            hn[hbase + reg * 8] = hb;
            if (layer == 0) {
                H0f[((size_t)t * 63 + rb) * 2048 + hbase + reg * 8] = hb;
            } else {
                int row = (l >> 4) * 4 + reg;
                if (row < nreal) hsum += h;
            }
        }
        if (layer == 1) {
            hsum += __shfl_xor(hsum, 16);
            hsum += __shfl_xor(hsum, 32);
            if ((l >> 4) == 0) atomicAdd(&pooled[t * 128 + d], hsum);
        }
        BAR();        // LDS-only: h writes ordered; Gx prefetch stays in flight
        p0 = q0; p1 = q1; p2 = q2; p3 = q3;
        cur ^= 1;
    }
    ((u64*)(hstate + (size_t)rb * 2048))[tid] = ((const u64*)(cur ? hshB : hshA))[tid];
    f32x4 cv = {cst0, cst1, cst2, cst3};
    *(f32x4*)(cstate + ((size_t)rb * 512 + tid) * 4) = cv;
}

// ---------- head ----------
__global__ void k_head(const float* __restrict__ pooled, const float* __restrict__ Wout,
                       const float* __restrict__ bout, float* __restrict__ out) {
    int gi = threadIdx.x;
    if (gi >= B_GR) return;
    float l0 = bout[0], l1 = bout[1];
    for (int d = 0; d < 128; ++d) {
        float p = pooled[gi * 128 + d] / 1000.0f;
        l0 += p * Wout[d * 2 + 0];
        l1 += p * Wout[d * 2 + 1];
    }
    float m = fmaxf(l0, l1);
    float lse = m + logf(__expf(l0 - m) + __expf(l1 - m));
    out[gi * 2 + 0] = l0 - lse;
    out[gi * 2 + 1] = l1 - lse;
}

// ---------- launch ----------
extern "C" void kernel_launch(void* const* d_in, const int* in_sizes, int n_in,
                              void* d_out, int out_size, void* d_ws, size_t ws_size,
                              hipStream_t stream) {
    const float* x    = (const float*)d_in[0];
    const int*   ei   = (const int*)d_in[1];
    const int*   srcI = ei;
    const int*   dstI = ei + E_EDGES;
    const float* Ws0  = (const float*)d_in[3];
    const float* Wn0  = (const float*)d_in[4];
    const float* b0   = (const float*)d_in[5];
    const float* Ws1  = (const float*)d_in[6];
    const float* Wn1  = (const float*)d_in[7];
    const float* b1   = (const float*)d_in[8];
    const float* Wih0 = (const float*)d_in[9];
    const float* Whh0 = (const float*)d_in[10];
    const float* bih0 = (const float*)d_in[11];
    const float* bhh0 = (const float*)d_in[12];
    const float* Wih1 = (const float*)d_in[13];
    const float* Whh1 = (const float*)d_in[14];
    const float* bih1 = (const float*)d_in[15];
    const float* bhh1 = (const float*)d_in[16];
    const float* Wout = (const float*)d_in[17];
    const float* bout = (const float*)d_in[18];
    float* out = (float*)d_out;

    char* ws = (char*)d_ws;
    // conv-phase layout
    int*   cnt    = (int*)(ws + 0);             // 400,128 B (padded)
    int*   ell    = (int*)(ws + 400128);        // 25,600,000 -> 26,000,128
    u16*   Hbf    = (u16*)(ws + 26000128);      // 25,600,000 -> 51,600,128
    u16*   AGbf   = (u16*)(ws + 51600128);      // 25,600,000 -> 77,200,128
    u16*   Xf     = (u16*)(ws + 77414400);      // 25,804,800 -> 103,219,200
    u16*   WTf    = (u16*)(ws + 103219200);     //    524,288 -> 103,743,488
    float* bsB    = (float*)(ws + 103743488);   //      4,096 -> 103,747,584
    float* pooled = (float*)(ws + 103747584);   //     51,200 -> 103,798,784
    u16*   hstate = (u16*)(ws + 103798784);     //    258,048 -> 104,056,832
    float* cstate = (float*)(ws + 104056832);   //    516,096 -> 104,572,928
    u16*   WCf    = (u16*)(ws + 104572928);     //    262,144 -> 104,835,072
    // LSTM-phase reuse (cnt/ell/Hbf/AGbf dead after conv1f):
    u16*   H0f    = (u16*)(ws + 0);             // 25,804,800 -> 25,804,800
    u16*   Gx     = (u16*)(ws + 25804800);      // 51,609,600 -> 77,414,400 (== Xf start)

    hipMemsetAsync(cnt, 0, 400128, stream);
    hipMemsetAsync(pooled, 0, B_GR * 128 * sizeof(float), stream);

    k_build<<<E_EDGES / 256, 256, 0, stream>>>(srcI, dstI, cnt, ell);
    k_conv0w<<<N_NODES / 4, 256, 0, stream>>>(x, cnt, ell, Ws0, Wn0, b0, Hbf);
    k_agg2e<<<N_NODES / 4, 256, 0, stream>>>(Hbf, cnt, ell, AGbf);
    k_prepc<<<32, 256, 0, stream>>>(Ws1, Wn1, WCf);

    hipFuncSetAttribute((const void*)k_conv1f, hipFuncAttributeMaxDynamicSharedMemorySize, 131072);
    hipFuncSetAttribute((const void*)k_gemmA,  hipFuncAttributeMaxDynamicSharedMemorySize, 131072);
    hipFuncSetAttribute((const void*)k_recB,   hipFuncAttributeMaxDynamicSharedMemorySize, 139264);

    k_conv1f<<<(N_NODES + 255) / 256, 256, 131072, stream>>>(Hbf, AGbf, WCf, b1, Xf);

    k_prepf<<<128, 256, 0, stream>>>(Wih0, Whh0, Wih1, Whh1, WTf);
    k_bsum<<<4, 256, 0, stream>>>(bih0, bhh0, bih1, bhh1, bsB);

    for (int layer = 0; layer < 2; ++layer) {
        const u16* srcT = layer ? H0f : Xf;
        for (int half = 0; half < 2; ++half) {
            int t0 = half * 50;
            k_gemmA<<<252, 512, 131072, stream>>>(srcT, WTf, bsB, Gx, t0, layer);
            k_recB<<<63, 512, 139264, stream>>>(Gx, WTf, H0f, pooled, hstate, cstate, t0, layer);
        }
    }

    k_head<<<1, 128, 0, stream>>>(pooled, Wout, bout, out);
}